// Round 8
// baseline (681.413 us; speedup 1.0000x reference)
//
#include <hip/hip_runtime.h>
#include <math.h>

#define NN 512
#define MM 31
#define TT 32            // M+1 tokens per node
#define EE 64            // INP = EMB = ATT
#define NREL 200
#define NMAT 201
#define SELF_LOOP 200
#define QCAP 192         // per-relation capacity (mean ~82, 12 sigma)
#define NT 6             // 32-token tiles per relation
#define WSTR 72          // bf16 LDS row stride
#define CPAD 32          // one counter per 128B line (round-6 verified win)
#define DONE_TOTAL 96    // 1 (prep k0) + 32*2 (q,v) + 31 (k)

typedef short  short8 __attribute__((ext_vector_type(8)));
typedef float  f32x4  __attribute__((ext_vector_type(4)));

__device__ __forceinline__ unsigned short f2bf(float f) {
    union { float f; unsigned int u; } a; a.f = f;
    unsigned int r = a.u + 0x7FFFu + ((a.u >> 16) & 1u);   // RNE
    return (unsigned short)(r >> 16);
}

// ---------------------------------------------------------------------------
// prep_convert: grid = 603 converter blocks + 512 node blocks (round-7 code
// + node_done seed of 1 per node).
// ---------------------------------------------------------------------------
__global__ __launch_bounds__(256) void prep_convert_kernel(
    const float* __restrict__ h, const float* __restrict__ W_self,
    const float* __restrict__ Q, const float* __restrict__ K,
    const float* __restrict__ V,
    const int* __restrict__ msg_type, const int* __restrict__ r_label_node,
    const int* __restrict__ r_label_msg,
    int* __restrict__ cnt_q, int* __restrict__ cnt_k,
    int* __restrict__ node_done,
    int* __restrict__ list_q, int* __restrict__ list_k,
    unsigned short* __restrict__ wt_q, unsigned short* __restrict__ wt_k,
    unsigned short* __restrict__ wt_v,
    float* __restrict__ curr_all, float* __restrict__ k_all)
{
    const int bid = blockIdx.x, tid = threadIdx.x;

    if (bid < 3 * NMAT) {
        // ---- converter: one [64,64] f32 -> transposed bf16 Wt[a][e] ----
        const int r   = bid % NMAT;
        const int mat = bid / NMAT;
        const float* src = (mat == 0 ? Q : mat == 1 ? K : V) + (size_t)r * EE * EE;
        unsigned short* dst = (mat == 0 ? wt_q : mat == 1 ? wt_k : wt_v)
                              + (size_t)r * EE * EE;
        __shared__ unsigned short t_s[EE * WSTR];

        {
            const int e = tid >> 2, aseg = (tid & 3) * 16;
            const float4* s4 = (const float4*)(src + e * EE + aseg);
            float4 f0 = s4[0], f1 = s4[1], f2 = s4[2], f3 = s4[3];
            unsigned short b[16] = {
                f2bf(f0.x), f2bf(f0.y), f2bf(f0.z), f2bf(f0.w),
                f2bf(f1.x), f2bf(f1.y), f2bf(f1.z), f2bf(f1.w),
                f2bf(f2.x), f2bf(f2.y), f2bf(f2.z), f2bf(f2.w),
                f2bf(f3.x), f2bf(f3.y), f2bf(f3.z), f2bf(f3.w) };
            unsigned short* d = &t_s[e * WSTR + aseg];
            *(short8*)d = *(short8*)&b[0];
            *(short8*)(d + 8) = *(short8*)&b[8];
        }
        __syncthreads();
        {
            const int a = tid >> 2, eseg = (tid & 3) * 16;
            unsigned short o[16];
#pragma unroll
            for (int j = 0; j < 16; ++j)
                o[j] = t_s[(eseg + j) * WSTR + a];
            unsigned short* d = dst + a * EE + eseg;
            *(short8*)d = *(short8*)&o[0];
            *(short8*)(d + 8) = *(short8*)&o[8];
        }
        return;
    }

    // ---- node block ----
    const int n = bid - 3 * NMAT;

    if (tid < MM) {
        int j  = n * MM + tid;
        int rl = r_label_msg[j];
        int p  = atomicAdd(&cnt_q[rl * CPAD], 1);
        if (p < QCAP) list_q[rl * QCAP + p] = n * TT + tid + 1;
        int mt = msg_type[j];
        int p2 = atomicAdd(&cnt_k[mt * CPAD], 1);
        if (p2 < QCAP) list_k[mt * QCAP + p2] = n * TT + tid + 1;
    } else if (tid == 63) {
        int r = r_label_node[n];
        int p = atomicAdd(&cnt_q[r * CPAD], 1);
        if (p < QCAP) list_q[r * QCAP + p] = n * TT;
    } else if (tid == 62) {
        atomicAdd(&node_done[n * CPAD], 1);   // visibility via dispatch boundary
    }

    __shared__ float c_s[EE];
    if (tid < EE) {
        const float* hrow = h + n * EE;
        float acc = 0.f;
#pragma unroll 8
        for (int e = 0; e < EE; ++e)
            acc = fmaf(hrow[e], W_self[e * EE + tid], acc);
        curr_all[n * EE + tid] = acc;
        c_s[tid] = acc;
    }
    __syncthreads();
    if (tid < EE) {
        const float* K200 = K + (size_t)SELF_LOOP * EE * EE;
        float k0 = 0.f;
#pragma unroll 8
        for (int e = 0; e < EE; ++e)
            k0 = fmaf(c_s[e], K200[e * EE + tid], k0);
        k_all[(size_t)n * TT * EE + tid] = k0;
    }
}

// ---------------------------------------------------------------------------
// proj_attn: block = (relation r, tile t). MFMA projection (verified r3-r7),
// then completion-count; the block that brings a node's counter to 96 runs
// that node's attention inline (threadfence-reduction pattern).
// ---------------------------------------------------------------------------
struct ProjS {
    unsigned short wq[EE * WSTR];
    unsigned short wk[EE * WSTR];
    unsigned short wv[EE * WSTR];
    unsigned short x[64 * WSTR];
};
struct AttnS {
    float q[TT][68], k[TT][68], v[TT][68];
    float s[TT][TT + 1];
    float att0[TT];
    float pooled[EE];
};
union SmemU { ProjS p; AttnS a; };

__global__ __launch_bounds__(256) void proj_attn_kernel(
    const float* __restrict__ curr_all, const float* __restrict__ msg,
    const unsigned short* __restrict__ wt_q,
    const unsigned short* __restrict__ wt_k,
    const unsigned short* __restrict__ wt_v,
    const int* __restrict__ cnt_q, const int* __restrict__ cnt_k,
    const int* __restrict__ list_q, const int* __restrict__ list_k,
    const float* __restrict__ ffn_w, const float* __restrict__ ffn_b,
    int* __restrict__ node_done,
    float* __restrict__ q_all, float* __restrict__ k_all,
    float* __restrict__ v_all, float* __restrict__ out)
{
    const int r    = blockIdx.x / NT;
    const int tile = blockIdx.x % NT;
    const int tid  = threadIdx.x;
    const int lane = tid & 63;
    const int wave = tid >> 6;
    const int col  = lane & 15;
    const int quad = lane >> 4;

    const int nq = min(cnt_q[r * CPAD], QCAP);
    const int nk = min(cnt_k[r * CPAD], QCAP);
    const int q0 = tile * 32;
    const bool do_q = q0 < nq;
    const bool do_k = q0 < nk;
    if (!do_q && !do_k) return;

    __shared__ SmemU sm;
    __shared__ int tq_s[32], tk_s[32];
    __shared__ int fin_cnt, fin_list[64];

    if (tid == 0) fin_cnt = 0;

    // ---- stage weights: pure bf16 copy ----
    {
        const int a = tid >> 2, seg = (tid & 3) * 16;
        const size_t go = (size_t)r * EE * EE + a * EE + seg;
        const int lo = a * WSTR + seg;
        if (do_q) {
            short8 w0 = *(const short8*)(wt_q + go);
            short8 w1 = *(const short8*)(wt_q + go + 8);
            *(short8*)&sm.p.wq[lo] = w0; *(short8*)&sm.p.wq[lo + 8] = w1;
            short8 v0 = *(const short8*)(wt_v + go);
            short8 v1 = *(const short8*)(wt_v + go + 8);
            *(short8*)&sm.p.wv[lo] = v0; *(short8*)&sm.p.wv[lo + 8] = v1;
        }
        if (do_k) {
            short8 k0_ = *(const short8*)(wt_k + go);
            short8 k1_ = *(const short8*)(wt_k + go + 8);
            *(short8*)&sm.p.wk[lo] = k0_; *(short8*)&sm.p.wk[lo + 8] = k1_;
        }
    }

    if (tid < 32) {
        tq_s[tid] = (do_q && q0 + tid < nq) ? list_q[r * QCAP + q0 + tid] : -1;
    } else if (tid < 64) {
        int i = tid - 32;
        tk_s[i] = (do_k && q0 + i < nk) ? list_k[r * QCAP + q0 + i] : -1;
    }

    // ---- stage x rows ----
    {
        const int row = tid >> 2;
        const int fo  = (tid & 3) * 4;
        const bool qside = row < 32;
        const int li = qside ? (q0 + row) : (q0 + row - 32);
        const bool valid = qside ? (do_q && li < nq) : (do_k && li < nk);
        if (valid) {
            int token = qside ? list_q[r * QCAP + li] : list_k[r * QCAP + li];
            int n = token >> 5, t = token & 31;
            const float* src = (t == 0)
                ? (curr_all + n * EE)
                : (msg + ((size_t)n * MM + (t - 1)) * EE);
            float4 f0 = ((const float4*)src)[fo + 0];
            float4 f1 = ((const float4*)src)[fo + 1];
            float4 f2 = ((const float4*)src)[fo + 2];
            float4 f3 = ((const float4*)src)[fo + 3];
            unsigned short b[16] = {
                f2bf(f0.x), f2bf(f0.y), f2bf(f0.z), f2bf(f0.w),
                f2bf(f1.x), f2bf(f1.y), f2bf(f1.z), f2bf(f1.w),
                f2bf(f2.x), f2bf(f2.y), f2bf(f2.z), f2bf(f2.w),
                f2bf(f3.x), f2bf(f3.y), f2bf(f3.z), f2bf(f3.w) };
            unsigned short* d = &sm.p.x[row * WSTR + fo * 4];
            *(short8*)d       = *(short8*)&b[0];
            *(short8*)(d + 8) = *(short8*)&b[8];
        }
    }
    __syncthreads();

    // ---- GEMM q/v ----
    if (do_q) {
        const int mtile = wave & 1;
        const unsigned short* w_s = (wave >> 1) ? sm.p.wv : sm.p.wq;
        float* outp = (wave >> 1) ? v_all : q_all;
        const int m = mtile * 16 + col;
        f32x4 acc[4] = {{0,0,0,0},{0,0,0,0},{0,0,0,0},{0,0,0,0}};
#pragma unroll
        for (int kk = 0; kk < 2; ++kk) {
            short8 af = *(const short8*)&sm.p.x[m * WSTR + kk * 32 + quad * 8];
#pragma unroll
            for (int nt = 0; nt < 4; ++nt) {
                short8 bf = *(const short8*)&w_s[(nt * 16 + col) * WSTR + kk * 32 + quad * 8];
                acc[nt] = __builtin_amdgcn_mfma_f32_16x16x32_bf16(af, bf, acc[nt], 0, 0, 0);
            }
        }
#pragma unroll
        for (int nt = 0; nt < 4; ++nt)
#pragma unroll
            for (int reg = 0; reg < 4; ++reg) {
                int rrow = mtile * 16 + quad * 4 + reg;
                int token = tq_s[rrow];
                if (token >= 0)
                    outp[(size_t)token * EE + nt * 16 + col] = acc[nt][reg];
            }
    }

    // ---- GEMM k ----
    if (do_k) {
        const int mtile = wave & 1;
        const int nh = wave >> 1;
        const int m = 32 + mtile * 16 + col;
        f32x4 acc[2] = {{0,0,0,0},{0,0,0,0}};
#pragma unroll
        for (int kk = 0; kk < 2; ++kk) {
            short8 af = *(const short8*)&sm.p.x[m * WSTR + kk * 32 + quad * 8];
#pragma unroll
            for (int j = 0; j < 2; ++j) {
                int nt = nh * 2 + j;
                short8 bf = *(const short8*)&sm.p.wk[(nt * 16 + col) * WSTR + kk * 32 + quad * 8];
                acc[j] = __builtin_amdgcn_mfma_f32_16x16x32_bf16(af, bf, acc[j], 0, 0, 0);
            }
        }
#pragma unroll
        for (int j = 0; j < 2; ++j)
#pragma unroll
            for (int reg = 0; reg < 4; ++reg) {
                int rrow = mtile * 16 + quad * 4 + reg;
                int token = tk_s[rrow];
                if (token >= 0)
                    k_all[(size_t)token * EE + (nh * 2 + j) * 16 + col] = acc[j][reg];
            }
    }

    // ---- completion counting (publish stores, then count) ----
    __syncthreads();         // all stores of this block issued
    __threadfence();         // release: make them device-visible
    int myfin = -1;
    if (tid < 32) {
        int token = tq_s[tid];
        if (token >= 0) {
            int n = token >> 5;
            int old = atomicAdd(&node_done[n * CPAD], 2);   // q + v rows
            if (old + 2 == DONE_TOTAL) myfin = n;
        }
    } else if (tid < 64) {
        int token = tk_s[tid - 32];
        if (token >= 0) {
            int n = token >> 5;
            int old = atomicAdd(&node_done[n * CPAD], 1);   // k row
            if (old + 1 == DONE_TOTAL) myfin = n;
        }
    }
    if (myfin >= 0) {
        int p = atomicAdd(&fin_cnt, 1);
        fin_list[p] = myfin;
    }
    __syncthreads();
    const int nf = fin_cnt;
    if (nf == 0) return;
    __threadfence();         // acquire: other blocks' qkv now visible

    // ---- inline attention for each finished node ----
    for (int f = 0; f < nf; ++f) {
        const int n = fin_list[f];
        {
            const float4* qg = (const float4*)(q_all + (size_t)n * TT * EE);
            const float4* kg = (const float4*)(k_all + (size_t)n * TT * EE);
            const float4* vg = (const float4*)(v_all + (size_t)n * TT * EE);
            for (int i = tid; i < TT * EE / 4; i += 256) {
                int row = i >> 4, c = i & 15;
                ((float4*)&sm.a.q[row][0])[c] = qg[i];
                ((float4*)&sm.a.k[row][0])[c] = kg[i];
                ((float4*)&sm.a.v[row][0])[c] = vg[i];
            }
        }
        __syncthreads();

        {   // scores
            const int ki = tid & 31;
            for (int qi = tid >> 5; qi < TT; qi += 8) {
                const float4* qp = (const float4*)&sm.a.q[qi][0];
                const float4* kp = (const float4*)&sm.a.k[ki][0];
                float acc = 0.f;
                for (int e4 = 0; e4 < EE / 4; ++e4) {
                    float4 aa = qp[e4], bb = kp[e4];
                    acc += aa.x * bb.x + aa.y * bb.y + aa.z * bb.z + aa.w * bb.w;
                }
                sm.a.s[qi][ki] = acc * 0.125f;
            }
        }
        __syncthreads();

        if (tid < TT) {   // softmax over QUERY axis per column; row 0 only
            float mx = -INFINITY;
            for (int qi = 0; qi < TT; ++qi) mx = fmaxf(mx, sm.a.s[qi][tid]);
            float sum = 0.f;
            for (int qi = 0; qi < TT; ++qi) sum += __expf(sm.a.s[qi][tid] - mx);
            sm.a.att0[tid] = __expf(sm.a.s[0][tid] - mx) / sum;
        }
        __syncthreads();

        if (tid < EE) {
            float acc = 0.f;
            for (int ki = 0; ki < TT; ++ki)
                acc = fmaf(sm.a.att0[ki], sm.a.v[ki][tid], acc);
            sm.a.pooled[tid] = acc;
        }
        __syncthreads();

        if (tid < EE) {
            float acc = ffn_b[tid];
            for (int a2 = 0; a2 < EE; ++a2)
                acc = fmaf(sm.a.pooled[a2], ffn_w[a2 * EE + tid], acc);
            out[n * EE + tid] = acc;
        }
        __syncthreads();   // protect sm.a before next iteration
    }
}

extern "C" void kernel_launch(void* const* d_in, const int* in_sizes, int n_in,
                              void* d_out, int out_size, void* d_ws, size_t ws_size,
                              hipStream_t stream) {
    const float* h            = (const float*)d_in[0];
    const float* msg          = (const float*)d_in[1];
    const int*   msg_type     = (const int*)  d_in[2];
    const int*   r_label_node = (const int*)  d_in[3];
    const int*   r_label_msg  = (const int*)  d_in[4];
    const float* W_self       = (const float*)d_in[5];
    const float* Q            = (const float*)d_in[6];
    const float* K            = (const float*)d_in[7];
    const float* V            = (const float*)d_in[8];
    const float* ffn_w        = (const float*)d_in[9];
    const float* ffn_b        = (const float*)d_in[10];
    float*       out          = (float*)d_out;

    // ws layout (16B aligned): counters | lists | bf16 weights | f32 bufs
    int* cnt_q     = (int*)d_ws;                       // [200*CPAD]
    int* cnt_k     = cnt_q + NREL * CPAD;              // [200*CPAD]
    int* node_done = cnt_k + NREL * CPAD;              // [512*CPAD]
    int* list_q    = node_done + NN * CPAD;            // [200*QCAP]
    int* list_k    = list_q + NREL * QCAP;             // [200*QCAP]
    unsigned short* wt_q = (unsigned short*)(list_k + NREL * QCAP);
    unsigned short* wt_k = wt_q + (size_t)NMAT * EE * EE;
    unsigned short* wt_v = wt_k + (size_t)NMAT * EE * EE;
    float* curr_all = (float*)(wt_v + (size_t)NMAT * EE * EE);
    float* q_all = curr_all + NN * EE;
    float* k_all = q_all + (size_t)NN * TT * EE;
    float* v_all = k_all + (size_t)NN * TT * EE;

    hipMemsetAsync(cnt_q, 0, (2 * NREL + NN) * CPAD * sizeof(int), stream);
    prep_convert_kernel<<<3 * NMAT + NN, 256, 0, stream>>>(
        h, W_self, Q, K, V, msg_type, r_label_node, r_label_msg,
        cnt_q, cnt_k, node_done, list_q, list_k, wt_q, wt_k, wt_v,
        curr_all, k_all);
    proj_attn_kernel<<<NREL * NT, 256, 0, stream>>>(
        curr_all, msg, wt_q, wt_k, wt_v, cnt_q, cnt_k, list_q, list_k,
        ffn_w, ffn_b, node_done, q_all, k_all, v_all, out);
}

// Round 9
// 107.133 us; speedup vs baseline: 6.3604x; 6.3604x over previous
//
#include <hip/hip_runtime.h>
#include <math.h>

#define NN 512
#define MM 31
#define TT 32            // M+1 tokens per node
#define EE 64            // INP = EMB = ATT
#define NREL 200
#define NMAT 201
#define SELF_LOOP 200
#define QCAP 192         // per-relation capacity (mean ~82, ~12 sigma)
#define NT 6             // 32-token tiles per relation
#define WSTR 72          // bf16 LDS row stride (16B-aligned, de-aliased banks)
#define CPAD 32          // one counter per 128B line (round-6 verified win)

typedef short  short8 __attribute__((ext_vector_type(8)));
typedef float  f32x4  __attribute__((ext_vector_type(4)));

__device__ __forceinline__ unsigned short f2bf(float f) {
    union { float f; unsigned int u; } a; a.f = f;
    unsigned int r = a.u + 0x7FFFu + ((a.u >> 16) & 1u);   // RNE
    return (unsigned short)(r >> 16);
}
__device__ __forceinline__ float bf2f(unsigned short u) {
    union { unsigned int u; float f; } a; a.u = ((unsigned int)u) << 16;
    return a.f;
}

// ---------------------------------------------------------------------------
// prep_convert: grid = 603 converter blocks + 512 node blocks.
//  bid < 603:  one [64,64] f32 Q/K/V matrix -> transposed bf16 Wt[a][e]
//  bid >= 603: node n: scan labels into buckets (padded counters),
//              msg[n] -> bf16 (coalesced), curr = h@W_self -> bf16,
//              k[n][0] = curr@K[200] -> bf16.
// ---------------------------------------------------------------------------
__global__ __launch_bounds__(256) void prep_convert_kernel(
    const float* __restrict__ h, const float* __restrict__ W_self,
    const float* __restrict__ Q, const float* __restrict__ K,
    const float* __restrict__ V,
    const int* __restrict__ msg_type, const int* __restrict__ r_label_node,
    const int* __restrict__ r_label_msg, const float* __restrict__ msg,
    int* __restrict__ cnt_q, int* __restrict__ cnt_k,
    int* __restrict__ list_q, int* __restrict__ list_k,
    unsigned short* __restrict__ wt_q, unsigned short* __restrict__ wt_k,
    unsigned short* __restrict__ wt_v,
    unsigned short* __restrict__ msg_bf, unsigned short* __restrict__ curr_bf,
    unsigned short* __restrict__ k_bf)
{
    const int bid = blockIdx.x, tid = threadIdx.x;

    if (bid < 3 * NMAT) {
        // ---- converter: one [64,64] f32 -> transposed bf16 Wt[a][e] ----
        const int r   = bid % NMAT;
        const int mat = bid / NMAT;
        const float* src = (mat == 0 ? Q : mat == 1 ? K : V) + (size_t)r * EE * EE;
        unsigned short* dst = (mat == 0 ? wt_q : mat == 1 ? wt_k : wt_v)
                              + (size_t)r * EE * EE;
        __shared__ unsigned short t_s[EE * WSTR];
        {
            const int e = tid >> 2, aseg = (tid & 3) * 16;
            const float4* s4 = (const float4*)(src + e * EE + aseg);
            float4 f0 = s4[0], f1 = s4[1], f2 = s4[2], f3 = s4[3];
            unsigned short b[16] = {
                f2bf(f0.x), f2bf(f0.y), f2bf(f0.z), f2bf(f0.w),
                f2bf(f1.x), f2bf(f1.y), f2bf(f1.z), f2bf(f1.w),
                f2bf(f2.x), f2bf(f2.y), f2bf(f2.z), f2bf(f2.w),
                f2bf(f3.x), f2bf(f3.y), f2bf(f3.z), f2bf(f3.w) };
            unsigned short* d = &t_s[e * WSTR + aseg];
            *(short8*)d = *(short8*)&b[0];
            *(short8*)(d + 8) = *(short8*)&b[8];
        }
        __syncthreads();
        {
            const int a = tid >> 2, eseg = (tid & 3) * 16;
            unsigned short o[16];
#pragma unroll
            for (int j = 0; j < 16; ++j)
                o[j] = t_s[(eseg + j) * WSTR + a];
            unsigned short* d = dst + a * EE + eseg;
            *(short8*)d = *(short8*)&o[0];
            *(short8*)(d + 8) = *(short8*)&o[8];
        }
        return;
    }

    // ---- node block ----
    const int n = bid - 3 * NMAT;

    // scan labels into padded relation buckets
    if (tid < MM) {
        int j  = n * MM + tid;
        int rl = r_label_msg[j];
        int p  = atomicAdd(&cnt_q[rl * CPAD], 1);
        if (p < QCAP) list_q[rl * QCAP + p] = n * TT + tid + 1;
        int mt = msg_type[j];
        int p2 = atomicAdd(&cnt_k[mt * CPAD], 1);
        if (p2 < QCAP) list_k[mt * QCAP + p2] = n * TT + tid + 1;
    } else if (tid == 63) {
        int r = r_label_node[n];
        int p = atomicAdd(&cnt_q[r * CPAD], 1);
        if (p < QCAP) list_q[r * QCAP + p] = n * TT;
    }

    // msg[n] -> bf16 (31*64 = 1984 floats; threads 0..247 do 8 each, coalesced)
    if (tid < MM * EE / 8) {
        const float4* s4 = (const float4*)(msg + (size_t)n * MM * EE) + tid * 2;
        float4 f0 = s4[0], f1 = s4[1];
        unsigned short b[8] = { f2bf(f0.x), f2bf(f0.y), f2bf(f0.z), f2bf(f0.w),
                                f2bf(f1.x), f2bf(f1.y), f2bf(f1.z), f2bf(f1.w) };
        *(short8*)(msg_bf + (size_t)n * MM * EE + tid * 8) = *(short8*)b;
    }

    // curr = h[n] @ W_self (f32 accum), publish bf16; k0 = curr @ K[200]
    __shared__ float c_s[EE];
    if (tid < EE) {
        const float* hrow = h + n * EE;
        float acc = 0.f;
#pragma unroll 8
        for (int e = 0; e < EE; ++e)
            acc = fmaf(hrow[e], W_self[e * EE + tid], acc);
        curr_bf[n * EE + tid] = f2bf(acc);
        c_s[tid] = acc;
    }
    __syncthreads();
    if (tid < EE) {
        const float* K200 = K + (size_t)SELF_LOOP * EE * EE;
        float k0 = 0.f;
#pragma unroll 8
        for (int e = 0; e < EE; ++e)
            k0 = fmaf(c_s[e], K200[e * EE + tid], k0);
        k_bf[(size_t)n * TT * EE + tid] = f2bf(k0);
    }
}

// ---------------------------------------------------------------------------
// proj_tile: block = (relation r, tile t). 32 q-tokens AND 32 k-tokens via
// 16x16x32 bf16 MFMA. All staging is now pure bf16 copies (weights AND x).
// Outputs stored bf16 (halves scatter bytes).
//   A[m=lane&15][k=(lane>>4)*8+j], B[k][n=lane&15] from Wt[a=n][e=k],
//   C: col=lane&15, row=(lane>>4)*4+reg  (verified rounds 3-7)
// ---------------------------------------------------------------------------
__global__ __launch_bounds__(256) void proj_tile_kernel(
    const unsigned short* __restrict__ curr_bf,
    const unsigned short* __restrict__ msg_bf,
    const unsigned short* __restrict__ wt_q,
    const unsigned short* __restrict__ wt_k,
    const unsigned short* __restrict__ wt_v,
    const int* __restrict__ cnt_q, const int* __restrict__ cnt_k,
    const int* __restrict__ list_q, const int* __restrict__ list_k,
    unsigned short* __restrict__ q_bf, unsigned short* __restrict__ k_bf,
    unsigned short* __restrict__ v_bf)
{
    const int r    = blockIdx.x / NT;
    const int tile = blockIdx.x % NT;
    const int tid  = threadIdx.x;
    const int lane = tid & 63;
    const int wave = tid >> 6;
    const int col  = lane & 15;
    const int quad = lane >> 4;

    const int nq = min(cnt_q[r * CPAD], QCAP);
    const int nk = min(cnt_k[r * CPAD], QCAP);
    const int q0 = tile * 32;
    const bool do_q = q0 < nq;
    const bool do_k = q0 < nk;
    if (!do_q && !do_k) return;

    __shared__ unsigned short wq_s[EE * WSTR];
    __shared__ unsigned short wk_s[EE * WSTR];
    __shared__ unsigned short wv_s[EE * WSTR];
    __shared__ unsigned short x_s[64 * WSTR];   // 0..31 q-side, 32..63 k-side
    __shared__ int tq_s[32], tk_s[32];

    // ---- stage weights: pure bf16 copy ----
    {
        const int a = tid >> 2, seg = (tid & 3) * 16;
        const size_t go = (size_t)r * EE * EE + a * EE + seg;
        const int lo = a * WSTR + seg;
        if (do_q) {
            short8 w0 = *(const short8*)(wt_q + go);
            short8 w1 = *(const short8*)(wt_q + go + 8);
            *(short8*)&wq_s[lo] = w0; *(short8*)&wq_s[lo + 8] = w1;
            short8 v0 = *(const short8*)(wt_v + go);
            short8 v1 = *(const short8*)(wt_v + go + 8);
            *(short8*)&wv_s[lo] = v0; *(short8*)&wv_s[lo + 8] = v1;
        }
        if (do_k) {
            short8 k0_ = *(const short8*)(wt_k + go);
            short8 k1_ = *(const short8*)(wt_k + go + 8);
            *(short8*)&wk_s[lo] = k0_; *(short8*)&wk_s[lo + 8] = k1_;
        }
    }

    if (tid < 32) {
        tq_s[tid] = (do_q && q0 + tid < nq) ? list_q[r * QCAP + q0 + tid] : -1;
    } else if (tid < 64) {
        int i = tid - 32;
        tk_s[i] = (do_k && q0 + i < nk) ? list_k[r * QCAP + q0 + i] : -1;
    }

    // ---- stage x rows: pure bf16 copy (4 threads/row, 16 shorts each) ----
    {
        const int row = tid >> 2;                // 0..63
        const int seg = (tid & 3) * 16;          // short offset in row
        const bool qside = row < 32;
        const int li = qside ? (q0 + row) : (q0 + row - 32);
        const bool valid = qside ? (do_q && li < nq) : (do_k && li < nk);
        if (valid) {
            int token = qside ? list_q[r * QCAP + li] : list_k[r * QCAP + li];
            int n = token >> 5, t = token & 31;
            const unsigned short* src = (t == 0)
                ? (curr_bf + n * EE)
                : (msg_bf + ((size_t)n * MM + (t - 1)) * EE);
            short8 s0 = *(const short8*)(src + seg);
            short8 s1 = *(const short8*)(src + seg + 8);
            unsigned short* d = &x_s[row * WSTR + seg];
            *(short8*)d = s0; *(short8*)(d + 8) = s1;
        }
    }
    __syncthreads();

    // ---- GEMM q/v (wave: mtile = w&1, mat = w>>1) ----
    if (do_q) {
        const int mtile = wave & 1;
        const unsigned short* w_s = (wave >> 1) ? wv_s : wq_s;
        unsigned short* outp = (wave >> 1) ? v_bf : q_bf;
        const int m = mtile * 16 + col;
        f32x4 acc[4] = {{0,0,0,0},{0,0,0,0},{0,0,0,0},{0,0,0,0}};
#pragma unroll
        for (int kk = 0; kk < 2; ++kk) {
            short8 af = *(const short8*)&x_s[m * WSTR + kk * 32 + quad * 8];
#pragma unroll
            for (int nt = 0; nt < 4; ++nt) {
                short8 bf = *(const short8*)&w_s[(nt * 16 + col) * WSTR + kk * 32 + quad * 8];
                acc[nt] = __builtin_amdgcn_mfma_f32_16x16x32_bf16(af, bf, acc[nt], 0, 0, 0);
            }
        }
#pragma unroll
        for (int nt = 0; nt < 4; ++nt)
#pragma unroll
            for (int reg = 0; reg < 4; ++reg) {
                int rrow = mtile * 16 + quad * 4 + reg;
                int token = tq_s[rrow];
                if (token >= 0)
                    outp[(size_t)token * EE + nt * 16 + col] = f2bf(acc[nt][reg]);
            }
    }

    // ---- GEMM k (wave: mtile = w&1, n-half = w>>1) ----
    if (do_k) {
        const int mtile = wave & 1;
        const int nh = wave >> 1;
        const int m = 32 + mtile * 16 + col;
        f32x4 acc[2] = {{0,0,0,0},{0,0,0,0}};
#pragma unroll
        for (int kk = 0; kk < 2; ++kk) {
            short8 af = *(const short8*)&x_s[m * WSTR + kk * 32 + quad * 8];
#pragma unroll
            for (int j = 0; j < 2; ++j) {
                int nt = nh * 2 + j;
                short8 bf = *(const short8*)&wk_s[(nt * 16 + col) * WSTR + kk * 32 + quad * 8];
                acc[j] = __builtin_amdgcn_mfma_f32_16x16x32_bf16(af, bf, acc[j], 0, 0, 0);
            }
        }
#pragma unroll
        for (int j = 0; j < 2; ++j)
#pragma unroll
            for (int reg = 0; reg < 4; ++reg) {
                int rrow = mtile * 16 + quad * 4 + reg;
                int token = tk_s[rrow];
                if (token >= 0)
                    k_bf[(size_t)token * EE + (nh * 2 + j) * 16 + col] = f2bf(acc[j][reg]);
            }
    }
}

// ---------------------------------------------------------------------------
// attn: one block per node; q/k/v are bf16 [32][64] rows, staged to f32 LDS.
// ---------------------------------------------------------------------------
__global__ __launch_bounds__(256) void attn_kernel(
    const unsigned short* __restrict__ q_bf,
    const unsigned short* __restrict__ k_bf,
    const unsigned short* __restrict__ v_bf,
    const float* __restrict__ ffn_w, const float* __restrict__ ffn_b,
    float* __restrict__ out)
{
    const int n = blockIdx.x, tid = threadIdx.x;
    __shared__ float q_s[TT][68], k_s[TT][68], v_s[TT][68];
    __shared__ float s_s[TT][TT + 1];
    __shared__ float att0[TT];
    __shared__ float pooled[EE];

    {   // stage + convert: thread -> one short8 per matrix (256 = 32 rows x 8)
        const int row = tid >> 3, c8 = (tid & 7) * 8;
        const size_t go = (size_t)n * TT * EE + row * EE + c8;
        short8 q8 = *(const short8*)(q_bf + go);
        short8 k8 = *(const short8*)(k_bf + go);
        short8 v8 = *(const short8*)(v_bf + go);
#pragma unroll
        for (int j = 0; j < 8; ++j) {
            q_s[row][c8 + j] = bf2f(((unsigned short*)&q8)[j]);
            k_s[row][c8 + j] = bf2f(((unsigned short*)&k8)[j]);
            v_s[row][c8 + j] = bf2f(((unsigned short*)&v8)[j]);
        }
    }
    __syncthreads();

    {   // scores s[qi][ki] = dot(q[qi],k[ki]) / 8
        const int ki = tid & 31;
        for (int qi = tid >> 5; qi < TT; qi += 8) {
            const float4* qp = (const float4*)&q_s[qi][0];
            const float4* kp = (const float4*)&k_s[ki][0];
            float acc = 0.f;
            for (int e4 = 0; e4 < EE / 4; ++e4) {
                float4 a = qp[e4], b = kp[e4];
                acc += a.x * b.x + a.y * b.y + a.z * b.z + a.w * b.w;
            }
            s_s[qi][ki] = acc * 0.125f;
        }
    }
    __syncthreads();

    // softmax over the QUERY axis per column; only row 0 of att needed
    if (tid < TT) {
        float mx = -INFINITY;
        for (int qi = 0; qi < TT; ++qi) mx = fmaxf(mx, s_s[qi][tid]);
        float sum = 0.f;
        for (int qi = 0; qi < TT; ++qi) sum += __expf(s_s[qi][tid] - mx);
        att0[tid] = __expf(s_s[0][tid] - mx) / sum;
    }
    __syncthreads();

    if (tid < EE) {
        float acc = 0.f;
        for (int ki = 0; ki < TT; ++ki)
            acc = fmaf(att0[ki], v_s[ki][tid], acc);
        pooled[tid] = acc;
    }
    __syncthreads();

    if (tid < EE) {
        float acc = ffn_b[tid];
        for (int a = 0; a < EE; ++a)
            acc = fmaf(pooled[a], ffn_w[a * EE + tid], acc);
        out[n * EE + tid] = acc;
    }
}

extern "C" void kernel_launch(void* const* d_in, const int* in_sizes, int n_in,
                              void* d_out, int out_size, void* d_ws, size_t ws_size,
                              hipStream_t stream) {
    const float* h            = (const float*)d_in[0];
    const float* msg          = (const float*)d_in[1];
    const int*   msg_type     = (const int*)  d_in[2];
    const int*   r_label_node = (const int*)  d_in[3];
    const int*   r_label_msg  = (const int*)  d_in[4];
    const float* W_self       = (const float*)d_in[5];
    const float* Q            = (const float*)d_in[6];
    const float* K            = (const float*)d_in[7];
    const float* V            = (const float*)d_in[8];
    const float* ffn_w        = (const float*)d_in[9];
    const float* ffn_b        = (const float*)d_in[10];
    float*       out          = (float*)d_out;

    // ws layout (16B aligned): counters | lists | bf16 weights | bf16 tensors
    int* cnt_q  = (int*)d_ws;                          // [200*CPAD]
    int* cnt_k  = cnt_q + NREL * CPAD;                 // [200*CPAD]
    int* list_q = cnt_k + NREL * CPAD;                 // [200*QCAP]
    int* list_k = list_q + NREL * QCAP;                // [200*QCAP]
    unsigned short* wt_q = (unsigned short*)(list_k + NREL * QCAP);
    unsigned short* wt_k = wt_q + (size_t)NMAT * EE * EE;
    unsigned short* wt_v = wt_k + (size_t)NMAT * EE * EE;
    unsigned short* msg_bf  = wt_v + (size_t)NMAT * EE * EE;     // [512*31*64]
    unsigned short* curr_bf = msg_bf + (size_t)NN * MM * EE;     // [512*64]
    unsigned short* q_bf = curr_bf + NN * EE;                    // [512*32*64]
    unsigned short* k_bf = q_bf + (size_t)NN * TT * EE;
    unsigned short* v_bf = k_bf + (size_t)NN * TT * EE;

    hipMemsetAsync(cnt_q, 0, 2 * NREL * CPAD * sizeof(int), stream);
    prep_convert_kernel<<<3 * NMAT + NN, 256, 0, stream>>>(
        h, W_self, Q, K, V, msg_type, r_label_node, r_label_msg, msg,
        cnt_q, cnt_k, list_q, list_k, wt_q, wt_k, wt_v,
        msg_bf, curr_bf, k_bf);
    proj_tile_kernel<<<NREL * NT, 256, 0, stream>>>(
        curr_bf, msg_bf, wt_q, wt_k, wt_v, cnt_q, cnt_k, list_q, list_k,
        q_bf, k_bf, v_bf);
    attn_kernel<<<NN, 256, 0, stream>>>(q_bf, k_bf, v_bf, ffn_w, ffn_b, out);
}